// Round 5
// baseline (222.735 us; speedup 1.0000x reference)
//
#include <hip/hip_runtime.h>
#include <math.h>
#include <stdint.h>

// GCNAgg: out = relu( (mean_s x[s]) * (1/sqrt(17)) @ W^T + b )
// x: [16][50000][256] fp32, W: [256][256] fp32, b: [256] fp32 -> out: [50000][256] fp32
//
// R5: split two-pass probe. Pass A = pure streaming reduce (819MB read @ max
// rate, bf16 mean -> ws). Pass B = MFMA GEMM from ws (L3-resident) + bias/ReLU.
// Decides whether ~4 TB/s read is a structural ceiling or a fused-structure
// artifact. Fused R4 kernel retained as fallback for small ws.

#define NSTACK 16
#define NNODES 50000
#define DIM    256
#define TM     64
#define LDSTRIDE 264
#define MEAN_OFF 131072                  // bytes into ws where mean[] starts (after Wbf 128KB)
#define NGRAN (NNODES * DIM / 4)         // 3,200,000 float4 granules
#define ABLOCKS (NGRAN / 256)            // 12500 reduce blocks
#define WBLOCKS 64                       // 64 blocks convert W (1024 elems each)

typedef __attribute__((ext_vector_type(8))) short  short8v;
typedef __attribute__((ext_vector_type(4))) float  float4v;

__device__ __forceinline__ unsigned short f2bf(float f) {
    unsigned int u = __float_as_uint(f);
    u += 0x7FFFu + ((u >> 16) & 1u);
    return (unsigned short)(u >> 16);
}

// ---------------- Pass A: streaming reduce + W convert (fused into one grid) --
__launch_bounds__(256, 4)
__global__ void meanw_kernel(const float* __restrict__ x,
                             const float* __restrict__ W,
                             unsigned short* __restrict__ Wbf,
                             unsigned short* __restrict__ mean,
                             float scale) {
    const int b = blockIdx.x;
    if (b >= ABLOCKS) {
        // W fp32 -> bf16: blocks [ABLOCKS, ABLOCKS+64), 256 thr x 4 elems
        const int i = ((b - ABLOCKS) * 256 + threadIdx.x) * 4;
        float4v w = *(const float4v*)(W + i);
        unsigned int lo = (unsigned int)f2bf(w.x) | ((unsigned int)f2bf(w.y) << 16);
        unsigned int hi = (unsigned int)f2bf(w.z) | ((unsigned int)f2bf(w.w) << 16);
        *(uint2*)(Wbf + i) = make_uint2(lo, hi);
        return;
    }
    // granule g covers x[.][g>>6][(g&63)*4 .. +3]; wave reads 1KB contiguous
    const int g = b * 256 + threadIdx.x;
    const float* p = x + (size_t)g * 4;
    float4v acc = (float4v){0.f, 0.f, 0.f, 0.f};
    #pragma unroll
    for (int s = 0; s < NSTACK; ++s) {
        acc += __builtin_nontemporal_load((const float4v*)(p + (size_t)s * NNODES * DIM));
    }
    acc *= scale;
    unsigned int lo = (unsigned int)f2bf(acc.x) | ((unsigned int)f2bf(acc.y) << 16);
    unsigned int hi = (unsigned int)f2bf(acc.z) | ((unsigned int)f2bf(acc.w) << 16);
    // normal (allocating) store: mean is re-read by pass B, want it in L2/L3
    *(uint2*)(mean + (size_t)g * 4) = make_uint2(lo, hi);
}

// ---------------- Pass B: MFMA GEMM from ws mean (bf16) ----------------------
__launch_bounds__(256, 4)
__global__ void gemm_kernel(const unsigned short* __restrict__ mean,
                            const unsigned short* __restrict__ Wbf,
                            const float* __restrict__ bias,
                            float* __restrict__ out) {
    const int t     = threadIdx.x;
    const int tile0 = blockIdx.x * TM;
    const int w   = t >> 6;
    const int l   = t & 63;
    const int l15 = l & 15;
    const int l4  = l >> 4;

    float4v acc[16];
    #pragma unroll
    for (int i = 0; i < 16; ++i) acc[i] = (float4v){0.f, 0.f, 0.f, 0.f};

    // clamp A-row so tail-block lanes read valid (duplicate) rows
    int arow = tile0 + w * 16 + l15;
    if (arow >= NNODES) arow = NNODES - 1;
    const unsigned short* abase = mean + (size_t)arow * DIM + l4 * 8;

    #pragma unroll
    for (int kb = 0; kb < 8; ++kb) {
        short8v afrag = *(const short8v*)(abase + kb * 32);
        #pragma unroll
        for (int cb = 0; cb < 16; ++cb) {
            short8v bfrag = *(const short8v*)(Wbf + (size_t)(cb * 16 + l15) * DIM + kb * 32 + l4 * 8);
            acc[cb] = __builtin_amdgcn_mfma_f32_16x16x32_bf16(afrag, bfrag, acc[cb], 0, 0, 0);
        }
    }

    #pragma unroll
    for (int cb = 0; cb < 16; ++cb) {
        const int col = cb * 16 + l15;
        const float bv = bias[col];
        #pragma unroll
        for (int r = 0; r < 4; ++r) {
            const int row = tile0 + w * 16 + l4 * 4 + r;
            if (row < NNODES) {
                float v = acc[cb][r] + bv;
                v = v > 0.f ? v : 0.f;
                __builtin_nontemporal_store(v, &out[(size_t)row * DIM + col]);
            }
        }
    }
}

// ---------------- Fallback: R4 fused kernel (small ws) -----------------------
__launch_bounds__(256, 4)
__global__ void gcn_fused_fb(const float* __restrict__ x,
                             const float* __restrict__ W,
                             const float* __restrict__ bias,
                             float* __restrict__ out,
                             float scale) {
    __shared__ unsigned short mlds[TM * LDSTRIDE];
    const int t     = threadIdx.x;
    const int tile0 = blockIdx.x * TM;
    {
        const int chg  = (t & 63) * 4;
        const int nsub = t >> 6;
        #pragma unroll 1
        for (int ng = 0; ng < 16; ++ng) {
            const int nl   = ng * 4 + nsub;
            const int node = tile0 + nl;
            float4v acc = (float4v){0.f, 0.f, 0.f, 0.f};
            if (node < NNODES) {
                const float* p = x + (size_t)node * DIM + chg;
                #pragma unroll
                for (int s = 0; s < NSTACK; ++s)
                    acc += __builtin_nontemporal_load((const float4v*)(p + (size_t)s * NNODES * DIM));
            }
            acc *= scale;
            unsigned int lo = (unsigned int)f2bf(acc.x) | ((unsigned int)f2bf(acc.y) << 16);
            unsigned int hi = (unsigned int)f2bf(acc.z) | ((unsigned int)f2bf(acc.w) << 16);
            *(uint2*)&mlds[nl * LDSTRIDE + chg] = make_uint2(lo, hi);
        }
    }
    __syncthreads();
    const int w = t >> 6, l = t & 63, l15 = l & 15, l4 = l >> 4;
    float4v acc[16];
    #pragma unroll
    for (int i = 0; i < 16; ++i) acc[i] = (float4v){0.f, 0.f, 0.f, 0.f};
    #pragma unroll
    for (int kb = 0; kb < 8; ++kb) {
        short8v afrag = *(const short8v*)&mlds[(w * 16 + l15) * LDSTRIDE + kb * 32 + l4 * 8];
        #pragma unroll
        for (int cb = 0; cb < 16; ++cb) {
            const float* wr = W + (size_t)(cb * 16 + l15) * DIM + kb * 32 + l4 * 8;
            float4v w0 = *(const float4v*)wr;
            float4v w1 = *(const float4v*)(wr + 4);
            short8v bfrag;
            bfrag[0] = (short)f2bf(w0.x); bfrag[1] = (short)f2bf(w0.y);
            bfrag[2] = (short)f2bf(w0.z); bfrag[3] = (short)f2bf(w0.w);
            bfrag[4] = (short)f2bf(w1.x); bfrag[5] = (short)f2bf(w1.y);
            bfrag[6] = (short)f2bf(w1.z); bfrag[7] = (short)f2bf(w1.w);
            acc[cb] = __builtin_amdgcn_mfma_f32_16x16x32_bf16(afrag, bfrag, acc[cb], 0, 0, 0);
        }
    }
    #pragma unroll
    for (int cb = 0; cb < 16; ++cb) {
        const int col = cb * 16 + l15;
        const float bv = bias[col];
        #pragma unroll
        for (int r = 0; r < 4; ++r) {
            const int row = tile0 + w * 16 + l4 * 4 + r;
            if (row < NNODES) {
                float v = acc[cb][r] + bv;
                v = v > 0.f ? v : 0.f;
                __builtin_nontemporal_store(v, &out[(size_t)row * DIM + col]);
            }
        }
    }
}

extern "C" void kernel_launch(void* const* d_in, const int* in_sizes, int n_in,
                              void* d_out, int out_size, void* d_ws, size_t ws_size,
                              hipStream_t stream) {
    const float* x  = (const float*)d_in[0];
    const float* W  = (const float*)d_in[1];
    const float* b  = (const float*)d_in[2];
    float* out      = (float*)d_out;

    const float scale = (float)(1.0 / (16.0 * sqrt(17.0)));
    const int nblocks = (NNODES + TM - 1) / TM;   // 782

    const size_t need = (size_t)MEAN_OFF + (size_t)NNODES * DIM * sizeof(unsigned short);
    if (ws_size >= need) {
        unsigned short* Wbf  = (unsigned short*)d_ws;
        unsigned short* mean = (unsigned short*)((char*)d_ws + MEAN_OFF);
        meanw_kernel<<<dim3(ABLOCKS + WBLOCKS), dim3(256), 0, stream>>>(x, W, Wbf, mean, scale);
        gemm_kernel<<<dim3(nblocks), dim3(256), 0, stream>>>(mean, Wbf, b, out);
    } else {
        gcn_fused_fb<<<dim3(nblocks), dim3(256), 0, stream>>>(x, W, b, out, scale);
    }
}

// Round 6
// 210.605 us; speedup vs baseline: 1.0576x; 1.0576x over previous
//
#include <hip/hip_runtime.h>
#include <math.h>
#include <stdint.h>

// GCNAgg: out = relu( (mean_s x[s]) * (1/sqrt(17)) @ W^T + b )
// x: [16][50000][256] fp32, W: [256][256] fp32 (row o, col i), b: [256] fp32
// out: [50000][256] fp32
//
// R6 = R4 (best, 209.5us): fused single-pass, nt loads on the 819MB x stream,
// nt stores on out, MFMA GEMM from LDS bf16 tile. R5's split-kernel probe
// established ~4.0-4.2 TB/s as the structural read ceiling for this pattern
// (pure stream w/o any compute read no faster); fused avoids the 77MB
// intermediate round-trip and overlaps GEMM+writes under the stream.

#define NSTACK 16
#define NNODES 50000
#define DIM    256
#define TM     64            // nodes per block
#define LDSTRIDE 264         // ushorts per LDS row (256 + 8 pad -> 528B stride)

typedef __attribute__((ext_vector_type(8))) short  short8v;   // 8 bf16 (MFMA A/B frag)
typedef __attribute__((ext_vector_type(4))) float  float4v;   // MFMA C/D frag

__device__ __forceinline__ unsigned short f2bf(float f) {
    unsigned int u = __float_as_uint(f);
    u += 0x7FFFu + ((u >> 16) & 1u);
    return (unsigned short)(u >> 16);
}

// Kernel 0: convert W fp32 -> bf16 row-major into workspace (65536 elems)
__global__ void wconv_kernel(const float* __restrict__ W, unsigned short* __restrict__ Wbf) {
    int i = (blockIdx.x * blockDim.x + threadIdx.x) * 4;
    float4v w = *(const float4v*)(W + i);
    unsigned int lo = (unsigned int)f2bf(w.x) | ((unsigned int)f2bf(w.y) << 16);
    unsigned int hi = (unsigned int)f2bf(w.z) | ((unsigned int)f2bf(w.w) << 16);
    *(uint2*)(Wbf + i) = make_uint2(lo, hi);
}

template <bool PACKED>
__launch_bounds__(256, 4)   // 4 waves/EU -> 4 blocks/CU (16 waves), VGPR cap 128
__global__ void gcn_fused(const float* __restrict__ x,
                          const float* __restrict__ W,
                          const unsigned short* __restrict__ Wbf,
                          const float* __restrict__ bias,
                          float* __restrict__ out,
                          float scale) {
    __shared__ unsigned short mlds[TM * LDSTRIDE];   // 33792 B -> 4 blocks/CU fits 160KB

    const int t     = threadIdx.x;
    const int tile0 = blockIdx.x * TM;

    // ---------- Phase 1: reduce 16 stacks -> scaled mean, bf16 into LDS ----------
    {
        const int chg  = (t & 63) * 4;   // channel start (float4 granule); wave covers one node row
        const int nsub = t >> 6;         // 0..3
        #pragma unroll 1                 // bound VGPR pressure: one 16-load batch in flight/thread
        for (int ng = 0; ng < 16; ++ng) {
            const int nl   = ng * 4 + nsub;      // local node 0..63
            const int node = tile0 + nl;
            float4v acc = (float4v){0.f, 0.f, 0.f, 0.f};
            if (node < NNODES) {
                const float* p = x + (size_t)node * DIM + chg;
                #pragma unroll
                for (int s = 0; s < NSTACK; ++s) {
                    float4v v = __builtin_nontemporal_load((const float4v*)(p + (size_t)s * NNODES * DIM));
                    acc += v;
                }
            }
            acc *= scale;
            unsigned int lo = (unsigned int)f2bf(acc.x) | ((unsigned int)f2bf(acc.y) << 16);
            unsigned int hi = (unsigned int)f2bf(acc.z) | ((unsigned int)f2bf(acc.w) << 16);
            *(uint2*)&mlds[nl * LDSTRIDE + chg] = make_uint2(lo, hi);
        }
    }
    __syncthreads();

    // ---------- Phase 2: per-wave 16x256 output tile via mfma_f32_16x16x32_bf16 ----------
    const int w   = t >> 6;     // wave 0..3 -> rows [w*16, w*16+16)
    const int l   = t & 63;
    const int l15 = l & 15;
    const int l4  = l >> 4;

    float4v acc[16];
    #pragma unroll
    for (int i = 0; i < 16; ++i) acc[i] = (float4v){0.f, 0.f, 0.f, 0.f};

    #pragma unroll
    for (int kb = 0; kb < 8; ++kb) {
        // A frag: lane l holds A[l&15][kb*32 + (l>>4)*8 + j], j=0..7
        const unsigned short* ap = &mlds[(w * 16 + l15) * LDSTRIDE + kb * 32 + l4 * 8];
        short8v afrag = *(const short8v*)ap;
        #pragma unroll
        for (int cb = 0; cb < 16; ++cb) {
            // B frag: lane l holds B[k][l&15] = W[cb*16 + (l&15)][k], k = kb*32 + (l>>4)*8 + j
            short8v bfrag;
            if (PACKED) {
                bfrag = *(const short8v*)(Wbf + (size_t)(cb * 16 + l15) * DIM + kb * 32 + l4 * 8);
            } else {
                const float* wr = W + (size_t)(cb * 16 + l15) * DIM + kb * 32 + l4 * 8;
                float4v w0 = *(const float4v*)wr;
                float4v w1 = *(const float4v*)(wr + 4);
                bfrag[0] = (short)f2bf(w0.x); bfrag[1] = (short)f2bf(w0.y);
                bfrag[2] = (short)f2bf(w0.z); bfrag[3] = (short)f2bf(w0.w);
                bfrag[4] = (short)f2bf(w1.x); bfrag[5] = (short)f2bf(w1.y);
                bfrag[6] = (short)f2bf(w1.z); bfrag[7] = (short)f2bf(w1.w);
            }
            acc[cb] = __builtin_amdgcn_mfma_f32_16x16x32_bf16(afrag, bfrag, acc[cb], 0, 0, 0);
        }
    }

    // ---------- Epilogue: +bias, ReLU, nontemporal store ------------------------
    #pragma unroll
    for (int cb = 0; cb < 16; ++cb) {
        const int col = cb * 16 + l15;
        const float bv = bias[col];
        #pragma unroll
        for (int r = 0; r < 4; ++r) {
            const int row = tile0 + w * 16 + l4 * 4 + r;
            if (row < NNODES) {
                float v = acc[cb][r] + bv;
                v = v > 0.f ? v : 0.f;
                __builtin_nontemporal_store(v, &out[(size_t)row * DIM + col]);
            }
        }
    }
}

extern "C" void kernel_launch(void* const* d_in, const int* in_sizes, int n_in,
                              void* d_out, int out_size, void* d_ws, size_t ws_size,
                              hipStream_t stream) {
    const float* x  = (const float*)d_in[0];
    const float* W  = (const float*)d_in[1];
    const float* b  = (const float*)d_in[2];
    float* out      = (float*)d_out;

    const float scale = (float)(1.0 / (16.0 * sqrt(17.0)));   // mean(1/16) * 1/sqrt(n+1)
    const int nblocks = (NNODES + TM - 1) / TM;               // 782

    const bool packed = ws_size >= (size_t)(DIM * DIM * sizeof(unsigned short));
    if (packed) {
        unsigned short* Wbf = (unsigned short*)d_ws;
        wconv_kernel<<<dim3((DIM * DIM / 4 + 255) / 256), dim3(256), 0, stream>>>(W, Wbf);
        gcn_fused<true><<<dim3(nblocks), dim3(256), 0, stream>>>(x, W, Wbf, b, out, scale);
    } else {
        gcn_fused<false><<<dim3(nblocks), dim3(256), 0, stream>>>(x, W, nullptr, b, out, scale);
    }
}